// Round 7
// baseline (229.584 us; speedup 1.0000x reference)
//
#include <hip/hip_runtime.h>
#include <hip/hip_bf16.h>

typedef __attribute__((ext_vector_type(8))) short bf16x8;
typedef __attribute__((ext_vector_type(4))) float f32x4;

#define NB 8
#define NN 2048
#define DM 512
#define DF 1024

__device__ __forceinline__ ushort f2b(float f) {
  union { __hip_bfloat16 h; ushort u; } c;
  c.h = __float2bfloat16(f);
  return c.u;
}
__device__ __forceinline__ float b2f(ushort u) {
  union { ushort u; __hip_bfloat16 h; } c;
  c.u = u;
  return __bfloat162float(c.h);
}

typedef __attribute__((address_space(1))) const void gvoid_t;
typedef __attribute__((address_space(3))) void svoid_t;
__device__ __forceinline__ void gload16(const void* g, void* s) {
  __builtin_amdgcn_global_load_lds((gvoid_t*)g, (svoid_t*)s, 16, 0, 0);
}

// ---------------- 128x128 NT GEMM core, double-buffered (gemm1/2, pv) ------
__device__ __forceinline__ void gemm_core_128(
    const ushort* __restrict__ A, const ushort* __restrict__ B,
    int K, int brow, int bcol, f32x4 (&acc)[4][4], ushort* smem)
{
  const int tid = threadIdx.x;
  const int w = tid >> 6, l = tid & 63;
  const int sr = (w << 3) + (l >> 3);
  const int sc = (((l & 7) ^ (l >> 3)) << 3);
  const int fr = l & 15;
  const int arow = ((w >> 1) << 6) + fr;
  const int brw  = ((w & 1) << 6) + fr;
  char* base = (char*)smem;
  char* A0 = base;          char* B0 = base + 16384;
  char* A1 = base + 32768;  char* B1 = base + 49152;

#pragma unroll
  for (int m = 0; m < 4; m++)
#pragma unroll
    for (int n = 0; n < 4; n++)
      acc[m][n] = (f32x4){0.f, 0.f, 0.f, 0.f};

  const ushort* Ap = A + (long)(brow + sr) * K + sc;
  const ushort* Bp = B + (long)(bcol + sr) * K + sc;
  const int nkt = K >> 6;

  auto stage = [&](char* Ad, char* Bd, int kt) {
#pragma unroll
    for (int i = 0; i < 4; i++) {
      gload16(Ap + (long)i * 32 * K + kt * 64, Ad + i * 4096 + (w << 10));
      gload16(Bp + (long)i * 32 * K + kt * 64, Bd + i * 4096 + (w << 10));
    }
  };
  auto compute = [&](const char* As_, const char* Bs_) {
#pragma unroll
    for (int kk = 0; kk < 2; kk++) {
      const int cx = ((((kk << 2) + (l >> 4)) ^ (l & 7)) << 4);
      bf16x8 a[4], b[4];
#pragma unroll
      for (int m = 0; m < 4; m++)
        a[m] = *(const bf16x8*)(As_ + (arow + m * 16) * 128 + cx);
#pragma unroll
      for (int n = 0; n < 4; n++)
        b[n] = *(const bf16x8*)(Bs_ + (brw + n * 16) * 128 + cx);
#pragma unroll
      for (int m = 0; m < 4; m++)
#pragma unroll
        for (int n = 0; n < 4; n++)
          acc[m][n] = __builtin_amdgcn_mfma_f32_16x16x32_bf16(a[m], b[n], acc[m][n], 0, 0, 0);
    }
  };

  stage(A0, B0, 0);
  __syncthreads();
  for (int kt = 0; kt < nkt; kt += 2) {
    stage(A1, B1, kt + 1);
    compute(A0, B0);
    __syncthreads();
    if (kt + 2 < nkt) stage(A0, B0, kt + 2);
    compute(A1, B1);
    __syncthreads();
  }
}

__device__ __forceinline__ void acc_to_lds_bf16(f32x4 (&acc)[4][4], ushort* smem) {
  const int tid = threadIdx.x, w = tid >> 6, l = tid & 63;
  const int r0l = ((w >> 1) << 6) + ((l >> 4) << 2);
  const int c0l = ((w & 1) << 6) + (l & 15);
#pragma unroll
  for (int n = 0; n < 4; n++)
#pragma unroll
    for (int m = 0; m < 4; m++)
#pragma unroll
      for (int j = 0; j < 4; j++)
        smem[(r0l + m * 16 + j) * 128 + (c0l + n * 16)] = f2b(acc[m][n][j]);
}

// ---------------- kernels ----------------

__global__ __launch_bounds__(256) void k_cvt(const float* __restrict__ in,
                                             ushort* __restrict__ out) {
  const long i = ((long)blockIdx.x * 256 + threadIdx.x) << 2;
  const float4 v = *(const float4*)(in + i);
  ushort4 o;
  o.x = f2b(v.x); o.y = f2b(v.y); o.z = f2b(v.z); o.w = f2b(v.w);
  *(ushort4*)(out + i) = o;
}

__device__ __forceinline__ float ld2f(const float* p, long i) { return p[i]; }
__device__ __forceinline__ float ld2f(const __hip_bfloat16* p, long i) { return __bfloat162float(p[i]); }

template <typename TIN>
__global__ __launch_bounds__(256) void k_tr(const TIN* __restrict__ in, ushort* __restrict__ out,
                                            int R, int C, long inB, long outB) {
  __shared__ float t[32][33];
  const long b = blockIdx.z;
  const TIN* ip = in + b * inB;
  ushort* op = out + b * outB;
  const int c0 = blockIdx.x << 5, r0 = blockIdx.y << 5;
  const int tx = threadIdx.x & 31, ty = threadIdx.x >> 5;
#pragma unroll
  for (int j = 0; j < 32; j += 8)
    t[ty + j][tx] = ld2f(ip, (long)(r0 + ty + j) * C + (c0 + tx));
  __syncthreads();
#pragma unroll
  for (int j = 0; j < 32; j += 8)
    op[(long)(c0 + ty + j) * R + (r0 + tx)] = f2b(t[tx][ty + j]);
}

__global__ __launch_bounds__(256) void k_gemm1(const ushort* __restrict__ xb,
                                               const ushort* __restrict__ w1t,
                                               const float* __restrict__ b1,
                                               ushort* __restrict__ hb) {
  __shared__ ushort smem[128 * 256];
  f32x4 acc[4][4];
  const int brow = blockIdx.x << 7, bcol = blockIdx.y << 7;
  gemm_core_128(xb, w1t, DM, brow, bcol, acc, smem);
  const int tid = threadIdx.x, w = tid >> 6, l = tid & 63;
  const int c0l = ((w & 1) << 6) + (l & 15);
#pragma unroll
  for (int n = 0; n < 4; n++) {
    const float bias = b1[bcol + c0l + n * 16];
#pragma unroll
    for (int m = 0; m < 4; m++)
#pragma unroll
      for (int j = 0; j < 4; j++) {
        float v = acc[m][n][j] + bias;
        acc[m][n][j] = v > 0.f ? v : 0.f;
      }
  }
  acc_to_lds_bf16(acc, smem);
  __syncthreads();
  const int rb = tid >> 4, cb = tid & 15;
#pragma unroll
  for (int i = 0; i < 8; i++) {
    const int row = i * 16 + rb;
    bf16x8 s = *(const bf16x8*)(smem + row * 128 + cb * 8);
    *(bf16x8*)(hb + (long)(brow + row) * DF + bcol + cb * 8) = s;
  }
}

__global__ __launch_bounds__(256) void k_gemm2(const ushort* __restrict__ hb,
                                               const ushort* __restrict__ w2t,
                                               const float* __restrict__ b2,
                                               ushort* __restrict__ kb,
                                               ushort* __restrict__ qb,
                                               ushort* __restrict__ vb) {
  __shared__ ushort smem[128 * 256];
  f32x4 acc[4][4];
  const int brow = blockIdx.x << 7, bcol = blockIdx.y << 7;
  gemm_core_128(hb, w2t, DF, brow, bcol, acc, smem);
  const int seg = bcol >> 9;  // 0:k 1:q 2:v
  ushort* dst = (seg == 0) ? kb : ((seg == 1) ? qb : vb);
  const float sc = (seg == 1) ? 0.04419417382415922f : 1.0f;  // 1/sqrt(512) into q
  const int tid = threadIdx.x, w = tid >> 6, l = tid & 63;
  const int c0l = ((w & 1) << 6) + (l & 15);
#pragma unroll
  for (int n = 0; n < 4; n++) {
    const float bias = b2[bcol + c0l + n * 16];
#pragma unroll
    for (int m = 0; m < 4; m++)
#pragma unroll
      for (int j = 0; j < 4; j++)
        acc[m][n][j] = (acc[m][n][j] + bias) * sc;
  }
  acc_to_lds_bf16(acc, smem);
  __syncthreads();
  const int rb = tid >> 4, cb = tid & 15;
  const int clb = bcol - (seg << 9);
#pragma unroll
  for (int i = 0; i < 8; i++) {
    const int row = i * 16 + rb;
    bf16x8 s = *(const bf16x8*)(smem + row * 128 + cb * 8);
    *(bf16x8*)(dst + (long)(brow + row) * DM + clb + cb * 8) = s;
  }
}

// ---------------- qk: 256x256 tile, 8 waves, counted-vmcnt 2-deep pipeline --
// Raw s_barrier + s_waitcnt vmcnt(8): the wait for tile kt+1's 8 loads happens
// one full compute phase after issue, and kt+2's loads stay in flight across
// the barrier (never drain to 0 in the main loop -- T4).
__global__ __launch_bounds__(512, 2) void k_qk256(const ushort* __restrict__ qb,
                                                  const ushort* __restrict__ kb,
                                                  const float* __restrict__ mask,
                                                  ushort* __restrict__ Sbuf) {
  __shared__ ushort smem[65536];  // 128 KB
  const int bid = blockIdx.x;     // 512 blocks
  const int batch = bid & 7;      // XCD-pinned
  const int tile = bid >> 3;      // 0..63
  const int brow = (tile & 7) << 8, bcol = (tile >> 3) << 8;
  const ushort* A = qb + (long)batch * NN * DM;
  const ushort* B = kb + (long)batch * NN * DM;
  const int K = DM;

  const int tid = threadIdx.x;
  const int w = tid >> 6, l = tid & 63;
  const int wr = w >> 2, wc = w & 3;
  const int fr = l & 15;
  char* bufbase = (char*)smem;

  f32x4 acc[8][4];
#pragma unroll
  for (int m = 0; m < 8; m++)
#pragma unroll
    for (int n = 0; n < 4; n++)
      acc[m][n] = (f32x4){0.f, 0.f, 0.f, 0.f};

  const int srow = (w << 3) + (l >> 3);            // 0..63
  const int sc = (((l & 7) ^ (l >> 3)) << 3);      // swizzled source chunk

  // stage full K-tile kt (A then B, 2 halves each = 8 loads/thread) into buf b
  auto stage_tile = [&](int b, int kt) {
#pragma unroll
    for (int mat = 0; mat < 2; ++mat) {
      const ushort* P = mat ? B : A;
      const int rbase = mat ? bcol : brow;
#pragma unroll
      for (int h = 0; h < 2; ++h) {
        char* dst = bufbase + (b << 16) + (mat << 15) + (h << 14) + (w << 10);
#pragma unroll
        for (int i = 0; i < 2; i++)
          gload16(P + (long)(rbase + (h << 7) + (i << 6) + srow) * K + (kt << 6) + sc,
                  dst + (i << 13));
      }
    }
  };

  auto compute = [&](int b) {
    const char* cA = bufbase + (b << 16);
    const char* cB = cA + 32768;
#pragma unroll
    for (int kk = 0; kk < 2; ++kk) {
      const int cx = ((((kk << 2) + (l >> 4)) ^ (l & 7)) << 4);
      bf16x8 bfrag[4];
#pragma unroll
      for (int n = 0; n < 4; n++)
        bfrag[n] = *(const bf16x8*)(cB + ((wc << 6) + (n << 4) + fr) * 128 + cx);
#pragma unroll
      for (int mh = 0; mh < 2; ++mh) {
        bf16x8 afrag[4];
#pragma unroll
        for (int mi = 0; mi < 4; mi++)
          afrag[mi] = *(const bf16x8*)(cA + ((wr << 7) + (mh << 6) + (mi << 4) + fr) * 128 + cx);
        __builtin_amdgcn_s_setprio(1);
#pragma unroll
        for (int mi = 0; mi < 4; mi++)
#pragma unroll
          for (int n = 0; n < 4; n++)
            acc[mh * 4 + mi][n] =
                __builtin_amdgcn_mfma_f32_16x16x32_bf16(afrag[mi], bfrag[n], acc[mh * 4 + mi][n], 0, 0, 0);
        __builtin_amdgcn_s_setprio(0);
      }
    }
  };

  // prologue: tiles 0 and 1 in flight; wait only for tile 0 (8 newest stay out)
  stage_tile(0, 0);
  stage_tile(1, 1);
  asm volatile("s_waitcnt vmcnt(8)" ::: "memory");
  __builtin_amdgcn_s_barrier();

  const int nkt = K >> 6;  // 8
  for (int kt = 0; kt < nkt; ++kt) {
    const int b = kt & 1;
    compute(b);
    __builtin_amdgcn_s_barrier();          // all waves done reading buf b
    if (kt + 2 < nkt) {
      stage_tile(b, kt + 2);               // refill freed buffer
      asm volatile("s_waitcnt vmcnt(8)" ::: "memory");  // tile kt+1 landed
    } else {
      asm volatile("s_waitcnt vmcnt(0)" ::: "memory");  // tail drain
    }
    __builtin_amdgcn_s_barrier();          // buf b^1 ready
  }

  // ---- epilogue: acc -> LDS (256x256 bf16, 16B-chunk XOR swizzle) ----
#pragma unroll
  for (int m = 0; m < 8; m++)
#pragma unroll
    for (int n = 0; n < 4; n++)
#pragma unroll
      for (int j = 0; j < 4; j++) {
        const int row = (wr << 7) + (m << 4) + ((l >> 4) << 2) + j;
        const int col = (wc << 6) + (n << 4) + fr;
        smem[row * 256 + (col ^ ((row & 7) << 3))] = f2b(acc[m][n][j]);
      }
  __syncthreads();

  // coalesced read-back + mask multiply + S store
  const float* mk = mask + (long)batch * NN * NN;
  ushort* S = Sbuf + (long)batch * NN * NN;
  const int rr = tid >> 4, cc = tid & 15;
#pragma unroll
  for (int i = 0; i < 8; ++i) {
    const int row = (i << 5) + rr;
    const long gr = (long)(brow + row) * NN + bcol;
#pragma unroll
    for (int hf = 0; hf < 2; ++hf) {
      const int ch = (hf << 4) + cc;  // 8-elem chunk 0..31
      bf16x8 s = *(const bf16x8*)(smem + row * 256 + ((ch ^ (row & 7)) << 3));
      const float4 m0 = *(const float4*)(mk + gr + ch * 8);
      const float4 m1 = *(const float4*)(mk + gr + ch * 8 + 4);
      bf16x8 o;
      o[0] = (short)f2b(b2f((ushort)s[0]) * m0.x);
      o[1] = (short)f2b(b2f((ushort)s[1]) * m0.y);
      o[2] = (short)f2b(b2f((ushort)s[2]) * m0.z);
      o[3] = (short)f2b(b2f((ushort)s[3]) * m0.w);
      o[4] = (short)f2b(b2f((ushort)s[4]) * m1.x);
      o[5] = (short)f2b(b2f((ushort)s[5]) * m1.y);
      o[6] = (short)f2b(b2f((ushort)s[6]) * m1.z);
      o[7] = (short)f2b(b2f((ushort)s[7]) * m1.w);
      *(bf16x8*)(S + gr + ch * 8) = o;
    }
  }
}

__global__ __launch_bounds__(256) void k_pv(const ushort* __restrict__ Sbuf,
                                            const ushort* __restrict__ vtb,
                                            float* __restrict__ out) {
  __shared__ ushort smem[128 * 256];
  const int batch = blockIdx.z;
  const ushort* A = Sbuf + (long)batch * NN * NN;
  const ushort* Bm = vtb + (long)batch * DM * NN;  // v^T [512][2048]
  float* op = out + (long)batch * NN * DM;
  f32x4 acc[4][4];
  const int brow = blockIdx.x << 7, bcol = blockIdx.y << 7;
  gemm_core_128(A, Bm, NN, brow, bcol, acc, smem);
  const int tid = threadIdx.x, w = tid >> 6, l = tid & 63;
  const int r0 = brow + ((w >> 1) << 6) + ((l >> 4) << 2);
  const int c0 = bcol + ((w & 1) << 6) + (l & 15);
#pragma unroll
  for (int n = 0; n < 4; n++) {
    const int c = c0 + n * 16;
#pragma unroll
    for (int m = 0; m < 4; m++) {
      const int r = r0 + m * 16;
#pragma unroll
      for (int j = 0; j < 4; j++)
        op[(long)(r + j) * DM + c] = acc[m][n][j];
    }
  }
}

// ---------------- launch ----------------
extern "C" void kernel_launch(void* const* d_in, const int* in_sizes, int n_in,
                              void* d_out, int out_size, void* d_ws, size_t ws_size,
                              hipStream_t stream) {
  const float* x    = (const float*)d_in[0];
  const float* mask = (const float*)d_in[1];
  const float* W1   = (const float*)d_in[2];
  const float* b1   = (const float*)d_in[3];
  const float* W2   = (const float*)d_in[4];
  const float* b2   = (const float*)d_in[5];
  float* out = (float*)d_out;

  char* ws = (char*)d_ws;
  size_t off = 0;
  auto alloc = [&](size_t n) { char* p = ws + off; off += (n + 255) & ~(size_t)255; return p; };
  ushort* xb  = (ushort*)alloc((size_t)NB * NN * DM * 2);
  ushort* hb  = (ushort*)alloc((size_t)NB * NN * DF * 2);
  ushort* w1t = (ushort*)alloc((size_t)DF * DM * 2);
  ushort* w2t = (ushort*)alloc((size_t)3 * DM * DF * 2);
  ushort* kb  = (ushort*)alloc((size_t)NB * NN * DM * 2);
  ushort* qb  = (ushort*)alloc((size_t)NB * NN * DM * 2);
  ushort* vb  = (ushort*)alloc((size_t)NB * NN * DM * 2);
  ushort* vtb = (ushort*)alloc((size_t)NB * NN * DM * 2);
  ushort* Sbuf = (ushort*)alloc((size_t)NB * NN * NN * 2);  // 67MB

  // x -> bf16
  k_cvt<<<dim3(8192), dim3(256), 0, stream>>>(x, xb);
  // W1 -> w1t ; W2 -> w2t
  k_tr<float><<<dim3(DF / 32, DM / 32, 1), dim3(256), 0, stream>>>(W1, w1t, DM, DF, 0, 0);
  k_tr<float><<<dim3(3 * DM / 32, DF / 32, 1), dim3(256), 0, stream>>>(W2, w2t, DF, 3 * DM, 0, 0);
  // h = relu(x@W1+b1)
  k_gemm1<<<dim3(NB * NN / 128, DF / 128), dim3(256), 0, stream>>>(xb, w1t, b1, hb);
  // kqv = h@W2+b2 (q pre-scaled)
  k_gemm2<<<dim3(NB * NN / 128, 3 * DM / 128), dim3(256), 0, stream>>>(hb, w2t, b2, kb, qb, vb);
  // v -> v^T per batch
  k_tr<__hip_bfloat16><<<dim3(DM / 32, NN / 32, NB), dim3(256), 0, stream>>>(
      (const __hip_bfloat16*)vb, vtb, NN, DM, (long)NN * DM, (long)DM * NN);
  // attention
  k_qk256<<<dim3(512), dim3(512), 0, stream>>>(qb, kb, mask, Sbuf);
  k_pv<<<dim3(NN / 128, DM / 128, NB), dim3(256), 0, stream>>>(Sbuf, vtb, out);
}

// Round 8
// 219.982 us; speedup vs baseline: 1.0437x; 1.0437x over previous
//
#include <hip/hip_runtime.h>
#include <hip/hip_bf16.h>

typedef __attribute__((ext_vector_type(8))) short bf16x8;
typedef __attribute__((ext_vector_type(4))) float f32x4;

#define NB 8
#define NN 2048
#define DM 512
#define DF 1024

__device__ __forceinline__ ushort f2b(float f) {
  union { __hip_bfloat16 h; ushort u; } c;
  c.h = __float2bfloat16(f);
  return c.u;
}
__device__ __forceinline__ float b2f(ushort u) {
  union { ushort u; __hip_bfloat16 h; } c;
  c.u = u;
  return __bfloat162float(c.h);
}

typedef __attribute__((address_space(1))) const void gvoid_t;
typedef __attribute__((address_space(3))) void svoid_t;
__device__ __forceinline__ void gload16(const void* g, void* s) {
  __builtin_amdgcn_global_load_lds((gvoid_t*)g, (svoid_t*)s, 16, 0, 0);
}

// ---------------- 128x128 NT GEMM core, double-buffered (gemm1/2, pv) ------
// 64 KB LDS. Measured (r3 vs r5): helps gemm1/gemm2/pv by ~6us total.
__device__ __forceinline__ void gemm_core_128(
    const ushort* __restrict__ A, const ushort* __restrict__ B,
    int K, int brow, int bcol, f32x4 (&acc)[4][4], ushort* smem)
{
  const int tid = threadIdx.x;
  const int w = tid >> 6, l = tid & 63;
  const int sr = (w << 3) + (l >> 3);
  const int sc = (((l & 7) ^ (l >> 3)) << 3);
  const int fr = l & 15;
  const int arow = ((w >> 1) << 6) + fr;
  const int brw  = ((w & 1) << 6) + fr;
  char* base = (char*)smem;
  char* A0 = base;          char* B0 = base + 16384;
  char* A1 = base + 32768;  char* B1 = base + 49152;

#pragma unroll
  for (int m = 0; m < 4; m++)
#pragma unroll
    for (int n = 0; n < 4; n++)
      acc[m][n] = (f32x4){0.f, 0.f, 0.f, 0.f};

  const ushort* Ap = A + (long)(brow + sr) * K + sc;
  const ushort* Bp = B + (long)(bcol + sr) * K + sc;
  const int nkt = K >> 6;

  auto stage = [&](char* Ad, char* Bd, int kt) {
#pragma unroll
    for (int i = 0; i < 4; i++) {
      gload16(Ap + (long)i * 32 * K + kt * 64, Ad + i * 4096 + (w << 10));
      gload16(Bp + (long)i * 32 * K + kt * 64, Bd + i * 4096 + (w << 10));
    }
  };
  auto compute = [&](const char* As_, const char* Bs_) {
#pragma unroll
    for (int kk = 0; kk < 2; kk++) {
      const int cx = ((((kk << 2) + (l >> 4)) ^ (l & 7)) << 4);
      bf16x8 a[4], b[4];
#pragma unroll
      for (int m = 0; m < 4; m++)
        a[m] = *(const bf16x8*)(As_ + (arow + m * 16) * 128 + cx);
#pragma unroll
      for (int n = 0; n < 4; n++)
        b[n] = *(const bf16x8*)(Bs_ + (brw + n * 16) * 128 + cx);
#pragma unroll
      for (int m = 0; m < 4; m++)
#pragma unroll
        for (int n = 0; n < 4; n++)
          acc[m][n] = __builtin_amdgcn_mfma_f32_16x16x32_bf16(a[m], b[n], acc[m][n], 0, 0, 0);
    }
  };

  stage(A0, B0, 0);
  __syncthreads();
  for (int kt = 0; kt < nkt; kt += 2) {
    stage(A1, B1, kt + 1);
    compute(A0, B0);
    __syncthreads();
    if (kt + 2 < nkt) stage(A0, B0, kt + 2);
    compute(A1, B1);
    __syncthreads();
  }
}

// ---------------- 128x128 NT GEMM core, single-buffered (qk) ---------------
// 32 KB LDS -> max blocks/CU. Best measured qk structure (r3: 83.7us).
__device__ __forceinline__ void gemm_core_128_sb(
    const ushort* __restrict__ A, const ushort* __restrict__ B,
    int K, int brow, int bcol, f32x4 (&acc)[4][4], ushort* smem)
{
  ushort* As = smem;
  ushort* Bs = smem + 128 * 64;
  const int tid = threadIdx.x;
  const int w = tid >> 6, l = tid & 63;
  const int sr = (w << 3) + (l >> 3);
  const int sc = (((l & 7) ^ (l >> 3)) << 3);
  char* AsB = (char*)As;
  char* BsB = (char*)Bs;
  const int fr = l & 15;
  const int arow = ((w >> 1) << 6) + fr;
  const int brw  = ((w & 1) << 6) + fr;

#pragma unroll
  for (int m = 0; m < 4; m++)
#pragma unroll
    for (int n = 0; n < 4; n++)
      acc[m][n] = (f32x4){0.f, 0.f, 0.f, 0.f};

  const ushort* Ap = A + (long)(brow + sr) * K + sc;
  const ushort* Bp = B + (long)(bcol + sr) * K + sc;
  const int nkt = K >> 6;
  for (int kt = 0; kt < nkt; ++kt) {
#pragma unroll
    for (int i = 0; i < 4; i++) {
      gload16(Ap + (long)i * 32 * K, AsB + i * 4096 + (w << 10));
      gload16(Bp + (long)i * 32 * K, BsB + i * 4096 + (w << 10));
    }
    Ap += 64; Bp += 64;
    __syncthreads();
#pragma unroll
    for (int kk = 0; kk < 2; kk++) {
      const int cx = ((((kk << 2) + (l >> 4)) ^ (l & 7)) << 4);
      bf16x8 a[4], b[4];
#pragma unroll
      for (int m = 0; m < 4; m++)
        a[m] = *(const bf16x8*)(AsB + (arow + m * 16) * 128 + cx);
#pragma unroll
      for (int n = 0; n < 4; n++)
        b[n] = *(const bf16x8*)(BsB + (brw + n * 16) * 128 + cx);
#pragma unroll
      for (int m = 0; m < 4; m++)
#pragma unroll
        for (int n = 0; n < 4; n++)
          acc[m][n] = __builtin_amdgcn_mfma_f32_16x16x32_bf16(a[m], b[n], acc[m][n], 0, 0, 0);
    }
    __syncthreads();
  }
}

__device__ __forceinline__ void acc_to_lds_bf16(f32x4 (&acc)[4][4], ushort* smem) {
  const int tid = threadIdx.x, w = tid >> 6, l = tid & 63;
  const int r0l = ((w >> 1) << 6) + ((l >> 4) << 2);
  const int c0l = ((w & 1) << 6) + (l & 15);
#pragma unroll
  for (int n = 0; n < 4; n++)
#pragma unroll
    for (int m = 0; m < 4; m++)
#pragma unroll
      for (int j = 0; j < 4; j++)
        smem[(r0l + m * 16 + j) * 128 + (c0l + n * 16)] = f2b(acc[m][n][j]);
}

// ---------------- kernels ----------------

__global__ __launch_bounds__(256) void k_cvt(const float* __restrict__ in,
                                             ushort* __restrict__ out) {
  const long i = ((long)blockIdx.x * 256 + threadIdx.x) << 2;
  const float4 v = *(const float4*)(in + i);
  ushort4 o;
  o.x = f2b(v.x); o.y = f2b(v.y); o.z = f2b(v.z); o.w = f2b(v.w);
  *(ushort4*)(out + i) = o;
}

__device__ __forceinline__ float ld2f(const float* p, long i) { return p[i]; }
__device__ __forceinline__ float ld2f(const __hip_bfloat16* p, long i) { return __bfloat162float(p[i]); }

template <typename TIN>
__global__ __launch_bounds__(256) void k_tr(const TIN* __restrict__ in, ushort* __restrict__ out,
                                            int R, int C, long inB, long outB) {
  __shared__ float t[32][33];
  const long b = blockIdx.z;
  const TIN* ip = in + b * inB;
  ushort* op = out + b * outB;
  const int c0 = blockIdx.x << 5, r0 = blockIdx.y << 5;
  const int tx = threadIdx.x & 31, ty = threadIdx.x >> 5;
#pragma unroll
  for (int j = 0; j < 32; j += 8)
    t[ty + j][tx] = ld2f(ip, (long)(r0 + ty + j) * C + (c0 + tx));
  __syncthreads();
#pragma unroll
  for (int j = 0; j < 32; j += 8)
    op[(long)(c0 + ty + j) * R + (r0 + tx)] = f2b(t[tx][ty + j]);
}

__global__ __launch_bounds__(256) void k_gemm1(const ushort* __restrict__ xb,
                                               const ushort* __restrict__ w1t,
                                               const float* __restrict__ b1,
                                               ushort* __restrict__ hb) {
  __shared__ ushort smem[128 * 256];
  f32x4 acc[4][4];
  const int brow = blockIdx.x << 7, bcol = blockIdx.y << 7;
  gemm_core_128(xb, w1t, DM, brow, bcol, acc, smem);
  const int tid = threadIdx.x, w = tid >> 6, l = tid & 63;
  const int c0l = ((w & 1) << 6) + (l & 15);
#pragma unroll
  for (int n = 0; n < 4; n++) {
    const float bias = b1[bcol + c0l + n * 16];
#pragma unroll
    for (int m = 0; m < 4; m++)
#pragma unroll
      for (int j = 0; j < 4; j++) {
        float v = acc[m][n][j] + bias;
        acc[m][n][j] = v > 0.f ? v : 0.f;
      }
  }
  acc_to_lds_bf16(acc, smem);
  __syncthreads();
  const int rb = tid >> 4, cb = tid & 15;
#pragma unroll
  for (int i = 0; i < 8; i++) {
    const int row = i * 16 + rb;
    bf16x8 s = *(const bf16x8*)(smem + row * 128 + cb * 8);
    *(bf16x8*)(hb + (long)(brow + row) * DF + bcol + cb * 8) = s;
  }
}

__global__ __launch_bounds__(256) void k_gemm2(const ushort* __restrict__ hb,
                                               const ushort* __restrict__ w2t,
                                               const float* __restrict__ b2,
                                               ushort* __restrict__ kb,
                                               ushort* __restrict__ qb,
                                               ushort* __restrict__ vb) {
  __shared__ ushort smem[128 * 256];
  f32x4 acc[4][4];
  const int brow = blockIdx.x << 7, bcol = blockIdx.y << 7;
  gemm_core_128(hb, w2t, DF, brow, bcol, acc, smem);
  const int seg = bcol >> 9;  // 0:k 1:q 2:v
  ushort* dst = (seg == 0) ? kb : ((seg == 1) ? qb : vb);
  const float sc = (seg == 1) ? 0.04419417382415922f : 1.0f;  // 1/sqrt(512) into q
  const int tid = threadIdx.x, w = tid >> 6, l = tid & 63;
  const int c0l = ((w & 1) << 6) + (l & 15);
#pragma unroll
  for (int n = 0; n < 4; n++) {
    const float bias = b2[bcol + c0l + n * 16];
#pragma unroll
    for (int m = 0; m < 4; m++)
#pragma unroll
      for (int j = 0; j < 4; j++)
        acc[m][n][j] = (acc[m][n][j] + bias) * sc;
  }
  acc_to_lds_bf16(acc, smem);
  __syncthreads();
  const int rb = tid >> 4, cb = tid & 15;
  const int clb = bcol - (seg << 9);
#pragma unroll
  for (int i = 0; i < 8; i++) {
    const int row = i * 16 + rb;
    bf16x8 s = *(const bf16x8*)(smem + row * 128 + cb * 8);
    *(bf16x8*)(dst + (long)(brow + row) * DM + clb + cb * 8) = s;
  }
}

// qk: single-buffered core (max occupancy), XCD swizzle, epilogue-batched
// mask loads (16 independent float4 issued together; regs born after acc dies
// so static VGPR max does not grow).
__global__ __launch_bounds__(256) void k_qk(const ushort* __restrict__ qb,
                                            const ushort* __restrict__ kb,
                                            const float* __restrict__ mask,
                                            ushort* __restrict__ Sbuf) {
  __shared__ ushort smem[128 * 128];  // 32 KB
  const int orig = blockIdx.x;
  const int swz = (orig & 7) * 256 + (orig >> 3);  // nwg=2048, bijective
  const int bx = swz & 15, by = (swz >> 4) & 15, batch = swz >> 8;
  const int brow = bx << 7, bcol = by << 7;
  const ushort* A = qb + (long)batch * NN * DM;
  const ushort* Bm = kb + (long)batch * NN * DM;
  const float* mk = mask + (long)batch * NN * NN;
  ushort* S = Sbuf + (long)batch * NN * NN;

  f32x4 acc[4][4];
  gemm_core_128_sb(A, Bm, DM, brow, bcol, acc, smem);
  acc_to_lds_bf16(acc, smem);
  __syncthreads();

  const int tid = threadIdx.x, rb = tid >> 4, cb = tid & 15;
  // phase 1: all mask loads issued back-to-back (MLP)
  float4 mreg[8][2];
#pragma unroll
  for (int i = 0; i < 8; i++) {
    const long goff = (long)(brow + i * 16 + rb) * NN + bcol + cb * 8;
    mreg[i][0] = *(const float4*)(mk + goff);
    mreg[i][1] = *(const float4*)(mk + goff + 4);
  }
  // phase 2: LDS read + multiply + coalesced store
#pragma unroll
  for (int i = 0; i < 8; i++) {
    const int row = i * 16 + rb;
    const long goff = (long)(brow + row) * NN + bcol + cb * 8;
    bf16x8 s = *(const bf16x8*)(smem + row * 128 + cb * 8);
    bf16x8 o;
    o[0] = (short)f2b(b2f((ushort)s[0]) * mreg[i][0].x);
    o[1] = (short)f2b(b2f((ushort)s[1]) * mreg[i][0].y);
    o[2] = (short)f2b(b2f((ushort)s[2]) * mreg[i][0].z);
    o[3] = (short)f2b(b2f((ushort)s[3]) * mreg[i][0].w);
    o[4] = (short)f2b(b2f((ushort)s[4]) * mreg[i][1].x);
    o[5] = (short)f2b(b2f((ushort)s[5]) * mreg[i][1].y);
    o[6] = (short)f2b(b2f((ushort)s[6]) * mreg[i][1].z);
    o[7] = (short)f2b(b2f((ushort)s[7]) * mreg[i][1].w);
    *(bf16x8*)(S + goff) = o;
  }
}

__global__ __launch_bounds__(256) void k_pv(const ushort* __restrict__ Sbuf,
                                            const ushort* __restrict__ vtb,
                                            float* __restrict__ out) {
  __shared__ ushort smem[128 * 256];
  const int batch = blockIdx.z;
  const ushort* A = Sbuf + (long)batch * NN * NN;
  const ushort* Bm = vtb + (long)batch * DM * NN;  // v^T [512][2048]
  float* op = out + (long)batch * NN * DM;
  f32x4 acc[4][4];
  const int brow = blockIdx.x << 7, bcol = blockIdx.y << 7;
  gemm_core_128(A, Bm, NN, brow, bcol, acc, smem);
  const int tid = threadIdx.x, w = tid >> 6, l = tid & 63;
  const int r0 = brow + ((w >> 1) << 6) + ((l >> 4) << 2);
  const int c0 = bcol + ((w & 1) << 6) + (l & 15);
#pragma unroll
  for (int n = 0; n < 4; n++) {
    const int c = c0 + n * 16;
#pragma unroll
    for (int m = 0; m < 4; m++) {
      const int r = r0 + m * 16;
#pragma unroll
      for (int j = 0; j < 4; j++)
        op[(long)(r + j) * DM + c] = acc[m][n][j];
    }
  }
}

// ---------------- launch ----------------
extern "C" void kernel_launch(void* const* d_in, const int* in_sizes, int n_in,
                              void* d_out, int out_size, void* d_ws, size_t ws_size,
                              hipStream_t stream) {
  const float* x    = (const float*)d_in[0];
  const float* mask = (const float*)d_in[1];
  const float* W1   = (const float*)d_in[2];
  const float* b1   = (const float*)d_in[3];
  const float* W2   = (const float*)d_in[4];
  const float* b2   = (const float*)d_in[5];
  float* out = (float*)d_out;

  char* ws = (char*)d_ws;
  size_t off = 0;
  auto alloc = [&](size_t n) { char* p = ws + off; off += (n + 255) & ~(size_t)255; return p; };
  ushort* xb  = (ushort*)alloc((size_t)NB * NN * DM * 2);
  ushort* hb  = (ushort*)alloc((size_t)NB * NN * DF * 2);
  ushort* w1t = (ushort*)alloc((size_t)DF * DM * 2);
  ushort* w2t = (ushort*)alloc((size_t)3 * DM * DF * 2);
  ushort* kb  = (ushort*)alloc((size_t)NB * NN * DM * 2);
  ushort* qb  = (ushort*)alloc((size_t)NB * NN * DM * 2);
  ushort* vb  = (ushort*)alloc((size_t)NB * NN * DM * 2);
  ushort* vtb = (ushort*)alloc((size_t)NB * NN * DM * 2);
  ushort* Sbuf = (ushort*)alloc((size_t)NB * NN * NN * 2);  // 67MB

  // x -> bf16
  k_cvt<<<dim3(8192), dim3(256), 0, stream>>>(x, xb);
  // W1 -> w1t ; W2 -> w2t
  k_tr<float><<<dim3(DF / 32, DM / 32, 1), dim3(256), 0, stream>>>(W1, w1t, DM, DF, 0, 0);
  k_tr<float><<<dim3(3 * DM / 32, DF / 32, 1), dim3(256), 0, stream>>>(W2, w2t, DF, 3 * DM, 0, 0);
  // h = relu(x@W1+b1)
  k_gemm1<<<dim3(NB * NN / 128, DF / 128), dim3(256), 0, stream>>>(xb, w1t, b1, hb);
  // kqv = h@W2+b2 (q pre-scaled)
  k_gemm2<<<dim3(NB * NN / 128, 3 * DM / 128), dim3(256), 0, stream>>>(hb, w2t, b2, kb, qb, vb);
  // v -> v^T per batch
  k_tr<__hip_bfloat16><<<dim3(DM / 32, NN / 32, NB), dim3(256), 0, stream>>>(
      (const __hip_bfloat16*)vb, vtb, NN, DM, (long)NN * DM, (long)DM * NN);
  // attention (split, S materialized in bf16)
  k_qk<<<dim3(2048), dim3(256), 0, stream>>>(qb, kb, mask, Sbuf);
  k_pv<<<dim3(NN / 128, DM / 128, NB), dim3(256), 0, stream>>>(Sbuf, vtb, out);
}

// Round 9
// 209.741 us; speedup vs baseline: 1.0946x; 1.0488x over previous
//
#include <hip/hip_runtime.h>
#include <hip/hip_bf16.h>

typedef __attribute__((ext_vector_type(8))) short bf16x8;
typedef __attribute__((ext_vector_type(4))) float f32x4;

#define NB 8
#define NN 2048
#define DM 512
#define DF 1024

__device__ __forceinline__ ushort f2b(float f) {
  union { __hip_bfloat16 h; ushort u; } c;
  c.h = __float2bfloat16(f);
  return c.u;
}
__device__ __forceinline__ float b2f(ushort u) {
  union { ushort u; __hip_bfloat16 h; } c;
  c.u = u;
  return __bfloat162float(c.h);
}

typedef __attribute__((address_space(1))) const void gvoid_t;
typedef __attribute__((address_space(3))) void svoid_t;
__device__ __forceinline__ void gload16(const void* g, void* s) {
  __builtin_amdgcn_global_load_lds((gvoid_t*)g, (svoid_t*)s, 16, 0, 0);
}

// ---------------- 128x128 NT GEMM core, double-buffered (gemm1/2, pv) ------
// 64 KB LDS. Measured (r3 vs r5): helps gemm1/gemm2/pv by ~6us total.
__device__ __forceinline__ void gemm_core_128(
    const ushort* __restrict__ A, const ushort* __restrict__ B,
    int K, int brow, int bcol, f32x4 (&acc)[4][4], ushort* smem)
{
  const int tid = threadIdx.x;
  const int w = tid >> 6, l = tid & 63;
  const int sr = (w << 3) + (l >> 3);
  const int sc = (((l & 7) ^ (l >> 3)) << 3);
  const int fr = l & 15;
  const int arow = ((w >> 1) << 6) + fr;
  const int brw  = ((w & 1) << 6) + fr;
  char* base = (char*)smem;
  char* A0 = base;          char* B0 = base + 16384;
  char* A1 = base + 32768;  char* B1 = base + 49152;

#pragma unroll
  for (int m = 0; m < 4; m++)
#pragma unroll
    for (int n = 0; n < 4; n++)
      acc[m][n] = (f32x4){0.f, 0.f, 0.f, 0.f};

  const ushort* Ap = A + (long)(brow + sr) * K + sc;
  const ushort* Bp = B + (long)(bcol + sr) * K + sc;
  const int nkt = K >> 6;

  auto stage = [&](char* Ad, char* Bd, int kt) {
#pragma unroll
    for (int i = 0; i < 4; i++) {
      gload16(Ap + (long)i * 32 * K + kt * 64, Ad + i * 4096 + (w << 10));
      gload16(Bp + (long)i * 32 * K + kt * 64, Bd + i * 4096 + (w << 10));
    }
  };
  auto compute = [&](const char* As_, const char* Bs_) {
#pragma unroll
    for (int kk = 0; kk < 2; kk++) {
      const int cx = ((((kk << 2) + (l >> 4)) ^ (l & 7)) << 4);
      bf16x8 a[4], b[4];
#pragma unroll
      for (int m = 0; m < 4; m++)
        a[m] = *(const bf16x8*)(As_ + (arow + m * 16) * 128 + cx);
#pragma unroll
      for (int n = 0; n < 4; n++)
        b[n] = *(const bf16x8*)(Bs_ + (brw + n * 16) * 128 + cx);
#pragma unroll
      for (int m = 0; m < 4; m++)
#pragma unroll
        for (int n = 0; n < 4; n++)
          acc[m][n] = __builtin_amdgcn_mfma_f32_16x16x32_bf16(a[m], b[n], acc[m][n], 0, 0, 0);
    }
  };

  stage(A0, B0, 0);
  __syncthreads();
  for (int kt = 0; kt < nkt; kt += 2) {
    stage(A1, B1, kt + 1);
    compute(A0, B0);
    __syncthreads();
    if (kt + 2 < nkt) stage(A0, B0, kt + 2);
    compute(A1, B1);
    __syncthreads();
  }
}

// ---------------- 128x128 NT GEMM core, single-buffered (qk) ---------------
// 32 KB LDS -> max blocks/CU. Best measured qk structure (r3: 83.7us).
__device__ __forceinline__ void gemm_core_128_sb(
    const ushort* __restrict__ A, const ushort* __restrict__ B,
    int K, int brow, int bcol, f32x4 (&acc)[4][4], ushort* smem)
{
  ushort* As = smem;
  ushort* Bs = smem + 128 * 64;
  const int tid = threadIdx.x;
  const int w = tid >> 6, l = tid & 63;
  const int sr = (w << 3) + (l >> 3);
  const int sc = (((l & 7) ^ (l >> 3)) << 3);
  char* AsB = (char*)As;
  char* BsB = (char*)Bs;
  const int fr = l & 15;
  const int arow = ((w >> 1) << 6) + fr;
  const int brw  = ((w & 1) << 6) + fr;

#pragma unroll
  for (int m = 0; m < 4; m++)
#pragma unroll
    for (int n = 0; n < 4; n++)
      acc[m][n] = (f32x4){0.f, 0.f, 0.f, 0.f};

  const ushort* Ap = A + (long)(brow + sr) * K + sc;
  const ushort* Bp = B + (long)(bcol + sr) * K + sc;
  const int nkt = K >> 6;
  for (int kt = 0; kt < nkt; ++kt) {
#pragma unroll
    for (int i = 0; i < 4; i++) {
      gload16(Ap + (long)i * 32 * K, AsB + i * 4096 + (w << 10));
      gload16(Bp + (long)i * 32 * K, BsB + i * 4096 + (w << 10));
    }
    Ap += 64; Bp += 64;
    __syncthreads();
#pragma unroll
    for (int kk = 0; kk < 2; kk++) {
      const int cx = ((((kk << 2) + (l >> 4)) ^ (l & 7)) << 4);
      bf16x8 a[4], b[4];
#pragma unroll
      for (int m = 0; m < 4; m++)
        a[m] = *(const bf16x8*)(AsB + (arow + m * 16) * 128 + cx);
#pragma unroll
      for (int n = 0; n < 4; n++)
        b[n] = *(const bf16x8*)(BsB + (brw + n * 16) * 128 + cx);
#pragma unroll
      for (int m = 0; m < 4; m++)
#pragma unroll
        for (int n = 0; n < 4; n++)
          acc[m][n] = __builtin_amdgcn_mfma_f32_16x16x32_bf16(a[m], b[n], acc[m][n], 0, 0, 0);
    }
    __syncthreads();
  }
}

__device__ __forceinline__ void acc_to_lds_bf16(f32x4 (&acc)[4][4], ushort* smem) {
  const int tid = threadIdx.x, w = tid >> 6, l = tid & 63;
  const int r0l = ((w >> 1) << 6) + ((l >> 4) << 2);
  const int c0l = ((w & 1) << 6) + (l & 15);
#pragma unroll
  for (int n = 0; n < 4; n++)
#pragma unroll
    for (int m = 0; m < 4; m++)
#pragma unroll
      for (int j = 0; j < 4; j++)
        smem[(r0l + m * 16 + j) * 128 + (c0l + n * 16)] = f2b(acc[m][n][j]);
}

// ---------------- kernels ----------------

__global__ __launch_bounds__(256) void k_cvt(const float* __restrict__ in,
                                             ushort* __restrict__ out) {
  const long i = ((long)blockIdx.x * 256 + threadIdx.x) << 2;
  const float4 v = *(const float4*)(in + i);
  ushort4 o;
  o.x = f2b(v.x); o.y = f2b(v.y); o.z = f2b(v.z); o.w = f2b(v.w);
  *(ushort4*)(out + i) = o;
}

// out[C][R] = (bf16) in[R][C]  (fp32 weights only)
__global__ __launch_bounds__(256) void k_trw(const float* __restrict__ in, ushort* __restrict__ out,
                                             int R, int C) {
  __shared__ float t[32][33];
  const int c0 = blockIdx.x << 5, r0 = blockIdx.y << 5;
  const int tx = threadIdx.x & 31, ty = threadIdx.x >> 5;
#pragma unroll
  for (int j = 0; j < 32; j += 8)
    t[ty + j][tx] = in[(long)(r0 + ty + j) * C + (c0 + tx)];
  __syncthreads();
#pragma unroll
  for (int j = 0; j < 32; j += 8)
    out[(long)(c0 + ty + j) * R + (r0 + tx)] = f2b(t[tx][ty + j]);
}

__global__ __launch_bounds__(256) void k_gemm1(const ushort* __restrict__ xb,
                                               const ushort* __restrict__ w1t,
                                               const float* __restrict__ b1,
                                               ushort* __restrict__ hb) {
  __shared__ ushort smem[128 * 256];
  f32x4 acc[4][4];
  const int brow = blockIdx.x << 7, bcol = blockIdx.y << 7;
  gemm_core_128(xb, w1t, DM, brow, bcol, acc, smem);
  const int tid = threadIdx.x, w = tid >> 6, l = tid & 63;
  const int c0l = ((w & 1) << 6) + (l & 15);
#pragma unroll
  for (int n = 0; n < 4; n++) {
    const float bias = b1[bcol + c0l + n * 16];
#pragma unroll
    for (int m = 0; m < 4; m++)
#pragma unroll
      for (int j = 0; j < 4; j++) {
        float v = acc[m][n][j] + bias;
        acc[m][n][j] = v > 0.f ? v : 0.f;
      }
  }
  acc_to_lds_bf16(acc, smem);
  __syncthreads();
  const int rb = tid >> 4, cb = tid & 15;
#pragma unroll
  for (int i = 0; i < 8; i++) {
    const int row = i * 16 + rb;
    bf16x8 s = *(const bf16x8*)(smem + row * 128 + cb * 8);
    *(bf16x8*)(hb + (long)(brow + row) * DF + bcol + cb * 8) = s;
  }
}

// gemm2: k,q stored row-major; v stored TRANSPOSED directly into vtb[d][n]
// (kills the separate v-transpose kernel + vb round-trip).
__global__ __launch_bounds__(256) void k_gemm2(const ushort* __restrict__ hb,
                                               const ushort* __restrict__ w2t,
                                               const float* __restrict__ b2,
                                               ushort* __restrict__ kb,
                                               ushort* __restrict__ qb,
                                               ushort* __restrict__ vtb) {
  __shared__ ushort smem[128 * 256];
  f32x4 acc[4][4];
  const int brow = blockIdx.x << 7, bcol = blockIdx.y << 7;
  gemm_core_128(hb, w2t, DF, brow, bcol, acc, smem);
  const int seg = bcol >> 9;  // 0:k 1:q 2:v
  const float sc = (seg == 1) ? 0.04419417382415922f : 1.0f;  // 1/sqrt(512) into q
  const int tid = threadIdx.x, w = tid >> 6, l = tid & 63;
  const int c0l = ((w & 1) << 6) + (l & 15);
#pragma unroll
  for (int n = 0; n < 4; n++) {
    const float bias = b2[bcol + c0l + n * 16];
#pragma unroll
    for (int m = 0; m < 4; m++)
#pragma unroll
      for (int j = 0; j < 4; j++)
        acc[m][n][j] = (acc[m][n][j] + bias) * sc;
  }
  acc_to_lds_bf16(acc, smem);
  __syncthreads();
  const int clb = bcol - (seg << 9);
  if (seg < 2) {
    ushort* dst = (seg == 0) ? kb : qb;
    const int rb = tid >> 4, cb = tid & 15;
#pragma unroll
    for (int i = 0; i < 8; i++) {
      const int row = i * 16 + rb;
      bf16x8 s = *(const bf16x8*)(smem + row * 128 + cb * 8);
      *(bf16x8*)(dst + (long)(brow + row) * DM + clb + cb * 8) = s;
    }
  } else {
    // transposed store: vtb[batch][clb+c][token]
    const int batch = brow >> 11;
    const int rbase = brow & 2047;
    const int c = tid & 127, rc = tid >> 7;
    ushort* vt = vtb + (long)batch * DM * NN + (long)(clb + c) * NN + rbase;
#pragma unroll
    for (int it = 0; it < 8; ++it) {
      const int chunk = rc * 8 + it;  // 0..15
      bf16x8 o;
#pragma unroll
      for (int j = 0; j < 8; ++j)
        o[j] = (short)smem[(chunk * 8 + j) * 128 + c];
      *(bf16x8*)(vt + chunk * 8) = o;
    }
  }
}

// qk: r3-exact form (best measured: 83.7us). 3-D grid, single-buffered core,
// inline mask loads in the LDS-roundtrip epilogue.
__global__ __launch_bounds__(256) void k_qk(const ushort* __restrict__ qb,
                                            const ushort* __restrict__ kb,
                                            const float* __restrict__ mask,
                                            ushort* __restrict__ Sbuf) {
  __shared__ ushort smem[128 * 128];
  const int batch = blockIdx.z;
  const ushort* A = qb + (long)batch * NN * DM;
  const ushort* Bm = kb + (long)batch * NN * DM;
  const float* mk = mask + (long)batch * NN * NN;
  ushort* S = Sbuf + (long)batch * NN * NN;
  f32x4 acc[4][4];
  const int brow = blockIdx.x << 7, bcol = blockIdx.y << 7;
  gemm_core_128_sb(A, Bm, DM, brow, bcol, acc, smem);
  acc_to_lds_bf16(acc, smem);
  __syncthreads();
  const int tid = threadIdx.x, rb = tid >> 4, cb = tid & 15;
#pragma unroll
  for (int i = 0; i < 8; i++) {
    const int row = i * 16 + rb;
    const long goff = (long)(brow + row) * NN + bcol + cb * 8;
    bf16x8 s = *(const bf16x8*)(smem + row * 128 + cb * 8);
    const float4 m0 = *(const float4*)(mk + goff);
    const float4 m1 = *(const float4*)(mk + goff + 4);
    bf16x8 o;
    o[0] = (short)f2b(b2f((ushort)s[0]) * m0.x);
    o[1] = (short)f2b(b2f((ushort)s[1]) * m0.y);
    o[2] = (short)f2b(b2f((ushort)s[2]) * m0.z);
    o[3] = (short)f2b(b2f((ushort)s[3]) * m0.w);
    o[4] = (short)f2b(b2f((ushort)s[4]) * m1.x);
    o[5] = (short)f2b(b2f((ushort)s[5]) * m1.y);
    o[6] = (short)f2b(b2f((ushort)s[6]) * m1.z);
    o[7] = (short)f2b(b2f((ushort)s[7]) * m1.w);
    *(bf16x8*)(S + goff) = o;
  }
}

__global__ __launch_bounds__(256) void k_pv(const ushort* __restrict__ Sbuf,
                                            const ushort* __restrict__ vtb,
                                            float* __restrict__ out) {
  __shared__ ushort smem[128 * 256];
  const int batch = blockIdx.z;
  const ushort* A = Sbuf + (long)batch * NN * NN;
  const ushort* Bm = vtb + (long)batch * DM * NN;  // v^T [512][2048]
  float* op = out + (long)batch * NN * DM;
  f32x4 acc[4][4];
  const int brow = blockIdx.x << 7, bcol = blockIdx.y << 7;
  gemm_core_128(A, Bm, NN, brow, bcol, acc, smem);
  // LDS-roundtrip fp32 epilogue: coalesced float4 stores (512B wave segments)
  float* fs = (float*)smem;  // 128x128 f32 = 64 KB, fits
  const int tid = threadIdx.x, w = tid >> 6, l = tid & 63;
  const int r0l = ((w >> 1) << 6) + ((l >> 4) << 2);
  const int c0l = ((w & 1) << 6) + (l & 15);
#pragma unroll
  for (int n = 0; n < 4; n++)
#pragma unroll
    for (int m = 0; m < 4; m++)
#pragma unroll
      for (int j = 0; j < 4; j++)
        fs[(r0l + m * 16 + j) * 128 + (c0l + n * 16)] = acc[m][n][j];
  __syncthreads();
  const int rg = tid >> 5, l32 = tid & 31;
#pragma unroll
  for (int p = 0; p < 16; ++p) {
    const int row = p * 8 + rg;
    const float4 v = *(const float4*)(fs + row * 128 + l32 * 4);
    *(float4*)(op + (long)(brow + row) * DM + bcol + l32 * 4) = v;
  }
}

// ---------------- launch ----------------
extern "C" void kernel_launch(void* const* d_in, const int* in_sizes, int n_in,
                              void* d_out, int out_size, void* d_ws, size_t ws_size,
                              hipStream_t stream) {
  const float* x    = (const float*)d_in[0];
  const float* mask = (const float*)d_in[1];
  const float* W1   = (const float*)d_in[2];
  const float* b1   = (const float*)d_in[3];
  const float* W2   = (const float*)d_in[4];
  const float* b2   = (const float*)d_in[5];
  float* out = (float*)d_out;

  char* ws = (char*)d_ws;
  size_t off = 0;
  auto alloc = [&](size_t n) { char* p = ws + off; off += (n + 255) & ~(size_t)255; return p; };
  ushort* xb  = (ushort*)alloc((size_t)NB * NN * DM * 2);
  ushort* hb  = (ushort*)alloc((size_t)NB * NN * DF * 2);
  ushort* w1t = (ushort*)alloc((size_t)DF * DM * 2);
  ushort* w2t = (ushort*)alloc((size_t)3 * DM * DF * 2);
  ushort* kb  = (ushort*)alloc((size_t)NB * NN * DM * 2);
  ushort* qb  = (ushort*)alloc((size_t)NB * NN * DM * 2);
  ushort* vtb = (ushort*)alloc((size_t)NB * NN * DM * 2);
  ushort* Sbuf = (ushort*)alloc((size_t)NB * NN * NN * 2);  // 67MB

  // x -> bf16
  k_cvt<<<dim3(8192), dim3(256), 0, stream>>>(x, xb);
  // W1 -> w1t ; W2 -> w2t
  k_trw<<<dim3(DF / 32, DM / 32), dim3(256), 0, stream>>>(W1, w1t, DM, DF);
  k_trw<<<dim3(3 * DM / 32, DF / 32), dim3(256), 0, stream>>>(W2, w2t, DF, 3 * DM);
  // h = relu(x@W1+b1)
  k_gemm1<<<dim3(NB * NN / 128, DF / 128), dim3(256), 0, stream>>>(xb, w1t, b1, hb);
  // kqv = h@W2+b2 (q pre-scaled; v written transposed into vtb)
  k_gemm2<<<dim3(NB * NN / 128, 3 * DM / 128), dim3(256), 0, stream>>>(hb, w2t, b2, kb, qb, vtb);
  // attention (split, S materialized in bf16)
  k_qk<<<dim3(NN / 128, NN / 128, NB), dim3(256), 0, stream>>>(qb, kb, mask, Sbuf);
  k_pv<<<dim3(NN / 128, DM / 128, NB), dim3(256), 0, stream>>>(Sbuf, vtb, out);
}